// Round 14
// baseline (48.547 us; speedup 1.0000x reference)
//
#include <hip/hip_runtime.h>
#include <hip/hip_bf16.h>
#include <math.h>

// Problem dims (fixed by reference)
constexpr int Bn = 8, Sn = 1024, Fn = 32, Dn = 128, Cc = 16;
constexpr int NSITE = Bn * Sn;

#define EPSV 1e-8f

typedef __attribute__((ext_vector_type(8))) short bf16x8;
typedef __attribute__((ext_vector_type(4))) short bf16x4;
typedef __attribute__((ext_vector_type(4))) float f32x4;

__device__ inline short f2bf(float x) {
    __hip_bfloat16 h = __float2bfloat16(x);   // RNE
    short s;
    __builtin_memcpy(&s, &h, sizeof(s));
    return s;
}

__device__ inline bf16x8 cvt8(f32x4 x0, f32x4 x1) {
    bf16x8 r;
    r[0] = f2bf(x0[0]); r[1] = f2bf(x0[1]); r[2] = f2bf(x0[2]); r[3] = f2bf(x0[3]);
    r[4] = f2bf(x1[0]); r[5] = f2bf(x1[1]); r[6] = f2bf(x1[2]); r[7] = f2bf(x1[3]);
    return r;
}

// ---- DPP 16-lane rotation all-reduce (VALU-latency, no LDS pipe) ----
template<int CTRL>
__device__ __forceinline__ float dpp_add(float v) {
    union { float f; int i; } u, r;
    u.f = v;
    r.i = __builtin_amdgcn_update_dpp(0, u.i, CTRL, 0xf, 0xf, true);
    return v + r.f;
}
__device__ __forceinline__ float rowsum16(float v) {
    v = dpp_add<0x121>(v);   // row_ror:1
    v = dpp_add<0x122>(v);   // row_ror:2
    v = dpp_add<0x124>(v);   // row_ror:4
    v = dpp_add<0x128>(v);   // row_ror:8
    return v;
}
__device__ __forceinline__ float fastrcp(float x) { return __builtin_amdgcn_rcpf(x); }

// ---------------------------------------------------------------------------
// Fused prep: blocks 0..63 pack W into bf16 MFMA B-fragment layout;
// blocks 64..79 normalize Cj and pack into the same layout.
// frag = (n>>4)*4 + (k>>5); lane = ((k>>3)&3)*16 + (n&15); j = k&7
// ---------------------------------------------------------------------------
__global__ void prep_kernel(const float* __restrict__ Cj,
                            const float* __restrict__ W,
                            short* __restrict__ CnPack,
                            short* __restrict__ Wb) {
    const int tid = threadIdx.x;
    if (blockIdx.x < 64) {
        int t = blockIdx.x * 256 + tid;   // 16384 total
        int n = t >> 7, k = t & 127;
        short v = f2bf(W[n * Dn + k]);
        int frag = (n >> 4) * 4 + (k >> 5);
        int lane = ((k >> 3) & 3) * 16 + (n & 15);
        Wb[(frag * 64 + lane) * 8 + (k & 7)] = v;
    } else {
        int c = blockIdx.x - 64;          // 16 blocks
        __shared__ float part[2];
        float v = 0.f, sq = 0.f;
        if (tid < 128) {
            v = Cj[c * Dn + tid];
            sq = v * v;
            #pragma unroll
            for (int off = 32; off > 0; off >>= 1) sq += __shfl_down(sq, off);
        }
        if (tid < 128 && (tid & 63) == 0) part[tid >> 6] = sq;
        __syncthreads();
        if (tid < 128) {
            float cn = v / fmaxf(sqrtf(part[0] + part[1]), EPSV);
            int kt = tid >> 5, ln = ((tid >> 3) & 3) * 16 + c, j = tid & 7;
            CnPack[(kt * 64 + ln) * 8 + j] = f2bf(cn);
        }
    }
}

// ---------------------------------------------------------------------------
// Site kernel: 4 independent waves per 256-thread block, one site each,
// NO barriers. Agg fused into the Linear nt-loop via a tiny per-wave
// ping-pong LDS tile ([2][16][40] = 2.5 KB/wave, intra-wave DS ordering).
// LDS/block 10240 B; __launch_bounds__(256,6) caps VGPR at 85 (r7/r13's
// code compiled to 84) -> 6 waves/SIMD = 24 waves/CU residency.
// ---------------------------------------------------------------------------
__launch_bounds__(256, 6)
__global__ void site_kernel(const float* __restrict__ Hs,
                            const short* __restrict__ CnPack,
                            const short* __restrict__ Wb,
                            const float* __restrict__ bvec,
                            const float* __restrict__ imp_in,
                            float* __restrict__ f_out,
                            float* __restrict__ imp_out) {
    // per-wave ping-pong F-tile: [wave][buf][n_local][feature], 80B rows
    __shared__ __align__(16) short Ft[4][2][16][40];   // 10240 B total

    const int lane = threadIdx.x & 63;
    const int wv   = threadIdx.x >> 6;
    const int c16  = lane & 15;
    const int g    = lane >> 4;
    const int site = blockIdx.x * 4 + wv;

    const float* hsrc = Hs + (size_t)site * (Fn * Dn);
    const f32x4 zro = {0.f, 0.f, 0.f, 0.f};

    // ---- issue all global loads early (16 x dwordx4 Hs) ----
    f32x4 x[16];
    #pragma unroll
    for (int kt = 0; kt < 4; ++kt) {
        const f32x4* p0 = (const f32x4*)(hsrc + c16 * Dn + kt * 32 + g * 8);
        const f32x4* p1 = (const f32x4*)(hsrc + (16 + c16) * Dn + kt * 32 + g * 8);
        x[4 * kt + 0] = p0[0];
        x[4 * kt + 1] = p0[1];
        x[4 * kt + 2] = p1[0];
        x[4 * kt + 3] = p1[1];
    }
    bf16x8 bcf[4];
    #pragma unroll
    for (int kt = 0; kt < 4; ++kt)
        bcf[kt] = *(const bf16x8*)&CnPack[(kt * 64 + lane) * 8];
    const float* impp = imp_in + (size_t)site * Fn;
    f32x4 impv0 = *(const f32x4*)(impp + 4 * g);        // imp[4g+r]
    f32x4 impv1 = *(const f32x4*)(impp + 16 + 4 * g);   // imp[16+4g+r]

    // ---- convert to bf16 A-fragments ----
    bf16x8 aF[2][4];
    #pragma unroll
    for (int kt = 0; kt < 4; ++kt) {
        aF[0][kt] = cvt8(x[4 * kt + 0], x[4 * kt + 1]);
        aF[1][kt] = cvt8(x[4 * kt + 2], x[4 * kt + 3]);
    }

    // ---- Gram (row norms via H.H^T diag) + cosine MFMAs (16 MFMA) ----
    f32x4 gm0 = zro, gm1 = zro, cos0 = zro, cos1 = zro;
    #pragma unroll
    for (int kt = 0; kt < 4; ++kt) {
        gm0  = __builtin_amdgcn_mfma_f32_16x16x32_bf16(aF[0][kt], aF[0][kt], gm0, 0, 0, 0);
        gm1  = __builtin_amdgcn_mfma_f32_16x16x32_bf16(aF[1][kt], aF[1][kt], gm1, 0, 0, 0);
        cos0 = __builtin_amdgcn_mfma_f32_16x16x32_bf16(aF[0][kt], bcf[kt], cos0, 0, 0, 0);
        cos1 = __builtin_amdgcn_mfma_f32_16x16x32_bf16(aF[1][kt], bcf[kt], cos1, 0, 0, 0);
    }

    // ---- logits s = 5*cos (softmax-shift-invariant), then e = exp(s).
    //      s in [-5,5] -> exp range-safe; e shared by BOTH softmaxes. ----
    float e0[4], e1[4];
    #pragma unroll
    for (int r = 0; r < 4; ++r) {
        float q0 = __shfl(gm0[r], 20 * g + r);      // diag gather (independent)
        float q1 = __shfl(gm1[r], 20 * g + r);
        float i0 = fastrcp(fmaxf(sqrtf(q0), EPSV));
        float i1 = fastrcp(fmaxf(sqrtf(q1), EPSV));
        e0[r] = __expf(5.0f * cos0[r] * i0);        // f = 4g+r,    c = c16
        e1[r] = __expf(5.0f * cos1[r] * i1);        // f = 16+4g+r, c = c16
    }

    // ---- w: softmax over features -> B-fragment via shuffles ----
    bf16x8 wB;
    {
        float sum = 0.f;
        #pragma unroll
        for (int r = 0; r < 4; ++r) sum += e0[r] + e1[r];
        sum += __shfl_xor(sum, 16);
        sum += __shfl_xor(sum, 32);
        float inv = fastrcp(sum);
        const int srcA = c16 + 16 * ((2 * g) & 3);
        const int srcB = c16 + 16 * ((2 * g + 1) & 3);
        const bool hi = (g >= 2);
        #pragma unroll
        for (int r = 0; r < 4; ++r) {
            float a0 = __shfl(e0[r] * inv, srcA);
            float a1 = __shfl(e1[r] * inv, srcA);
            wB[r] = f2bf(hi ? a1 : a0);
            float b0 = __shfl(e0[r] * inv, srcB);
            float b1 = __shfl(e1[r] * inv, srcB);
            wB[4 + r] = f2bf(hi ? b1 : b0);
        }
    }

    // ---- w3 softmax over centers (DPP row-sums) fused with importance ----
    {
        float t = 0.f;
        #pragma unroll
        for (int h = 0; h < 2; ++h) {
            #pragma unroll
            for (int r = 0; r < 4; ++r) {
                float e = h ? e1[r] : e0[r];
                float q3 = rowsum16(e);             // sum over c (16-lane row)
                t += e * fastrcp(q3) * (h ? impv1[r] : impv0[r]);
            }
        }
        t += __shfl_xor(t, 16);
        t += __shfl_xor(t, 32);
        // importance softmax over c: t <= 32 -> exp safe without max
        float ei = __expf(t);
        float si = rowsum16(ei);
        if (g == 0) imp_out[(size_t)site * Cc + c16] = ei * fastrcp(si);
    }

    // ---- fused Linear + agg: per nt, Linear MFMAs -> tiny LDS tile ->
    //      transposed read -> agg MFMA -> coalesced float4 store ----
    float* op = f_out + (size_t)site * (Cc * Dn);
    #pragma unroll
    for (int nt = 0; nt < 8; ++nt) {
        bf16x8 bw0 = *(const bf16x8*)&Wb[((nt * 4) + 0) * 512 + lane * 8];
        bf16x8 bw1 = *(const bf16x8*)&Wb[((nt * 4) + 1) * 512 + lane * 8];
        bf16x8 bw2 = *(const bf16x8*)&Wb[((nt * 4) + 2) * 512 + lane * 8];
        bf16x8 bw3 = *(const bf16x8*)&Wb[((nt * 4) + 3) * 512 + lane * 8];
        f32x4 acc0 = zro, acc1 = zro;
        acc0 = __builtin_amdgcn_mfma_f32_16x16x32_bf16(aF[0][0], bw0, acc0, 0, 0, 0);
        acc1 = __builtin_amdgcn_mfma_f32_16x16x32_bf16(aF[1][0], bw0, acc1, 0, 0, 0);
        acc0 = __builtin_amdgcn_mfma_f32_16x16x32_bf16(aF[0][1], bw1, acc0, 0, 0, 0);
        acc1 = __builtin_amdgcn_mfma_f32_16x16x32_bf16(aF[1][1], bw1, acc1, 0, 0, 0);
        acc0 = __builtin_amdgcn_mfma_f32_16x16x32_bf16(aF[0][2], bw2, acc0, 0, 0, 0);
        acc1 = __builtin_amdgcn_mfma_f32_16x16x32_bf16(aF[1][2], bw2, acc1, 0, 0, 0);
        acc0 = __builtin_amdgcn_mfma_f32_16x16x32_bf16(aF[0][3], bw3, acc0, 0, 0, 0);
        acc1 = __builtin_amdgcn_mfma_f32_16x16x32_bf16(aF[1][3], bw3, acc1, 0, 0, 0);
        float bb = bvec[nt * 16 + c16];
        bf16x4 p0, p1;
        #pragma unroll
        for (int r = 0; r < 4; ++r) {
            p0[r] = f2bf(fmaxf(acc0[r] + bb, 0.f));
            p1[r] = f2bf(fmaxf(acc1[r] + bb, 0.f));
        }
        // lane holds F[f=4g+r | 16+4g+r][n = 16nt+c16] -> tile row c16
        *(bf16x4*)&Ft[wv][nt & 1][c16][4 * g]      = p0;   // f = 4g+r
        *(bf16x4*)&Ft[wv][nt & 1][c16][16 + 4 * g] = p1;   // f = 16+4g+r
        // transposed read: A-frag for agg = F^T[n_local=c16][f=8g+j]
        bf16x8 aFt = *(const bf16x8*)&Ft[wv][nt & 1][c16][8 * g];
        f32x4 o = __builtin_amdgcn_mfma_f32_16x16x32_bf16(aFt, wB, zro, 0, 0, 0);
        *(f32x4*)(op + c16 * Dn + nt * 16 + 4 * g) = o;
    }
}

// ---------------------------------------------------------------------------
extern "C" void kernel_launch(void* const* d_in, const int* in_sizes, int n_in,
                              void* d_out, int out_size, void* d_ws, size_t ws_size,
                              hipStream_t stream) {
    const float* Hs  = (const float*)d_in[0];
    const float* Cj  = (const float*)d_in[1];
    const float* W   = (const float*)d_in[2];
    const float* b   = (const float*)d_in[3];
    const float* imp = (const float*)d_in[4];

    float* f_out   = (float*)d_out;                          // [B,S,C,D]
    float* imp_out = f_out + (size_t)NSITE * Cc * Dn;        // [B,S,C]

    short* CnPack = (short*)d_ws;                            // 4 KB bf16 frags
    short* Wb     = CnPack + Cc * Dn;                        // 32 KB bf16 frags

    hipLaunchKernelGGL(prep_kernel, dim3(80), dim3(256), 0, stream, Cj, W, CnPack, Wb);
    hipLaunchKernelGGL(site_kernel, dim3(NSITE / 4), dim3(256), 0, stream,
                       Hs, CnPack, Wb, b, imp, f_out, imp_out);
}

// Round 15
// 48.442 us; speedup vs baseline: 1.0022x; 1.0022x over previous
//
#include <hip/hip_runtime.h>
#include <hip/hip_bf16.h>
#include <math.h>

// Problem dims (fixed by reference)
constexpr int Bn = 8, Sn = 1024, Fn = 32, Dn = 128, Cc = 16;
constexpr int NSITE = Bn * Sn;

#define EPSV 1e-8f

typedef __attribute__((ext_vector_type(8))) short bf16x8;
typedef __attribute__((ext_vector_type(4))) short bf16x4;
typedef __attribute__((ext_vector_type(4))) float f32x4;

__device__ inline short f2bf(float x) {
    __hip_bfloat16 h = __float2bfloat16(x);   // RNE
    short s;
    __builtin_memcpy(&s, &h, sizeof(s));
    return s;
}

__device__ inline bf16x8 cvt8(f32x4 x0, f32x4 x1) {
    bf16x8 r;
    r[0] = f2bf(x0[0]); r[1] = f2bf(x0[1]); r[2] = f2bf(x0[2]); r[3] = f2bf(x0[3]);
    r[4] = f2bf(x1[0]); r[5] = f2bf(x1[1]); r[6] = f2bf(x1[2]); r[7] = f2bf(x1[3]);
    return r;
}

// ---- DPP 16-lane rotation all-reduce (VALU-latency, no LDS pipe) ----
template<int CTRL>
__device__ __forceinline__ float dpp_add(float v) {
    union { float f; int i; } u, r;
    u.f = v;
    r.i = __builtin_amdgcn_update_dpp(0, u.i, CTRL, 0xf, 0xf, true);
    return v + r.f;
}
__device__ __forceinline__ float rowsum16(float v) {
    v = dpp_add<0x121>(v);   // row_ror:1
    v = dpp_add<0x122>(v);   // row_ror:2
    v = dpp_add<0x124>(v);   // row_ror:4
    v = dpp_add<0x128>(v);   // row_ror:8
    return v;
}
__device__ __forceinline__ float fastrcp(float x) { return __builtin_amdgcn_rcpf(x); }

// ---------------------------------------------------------------------------
// Fused prep: blocks 0..63 pack W into bf16 MFMA B-fragment layout;
// blocks 64..79 normalize Cj and pack into the same layout.
// frag = (n>>4)*4 + (k>>5); lane = ((k>>3)&3)*16 + (n&15); j = k&7
// ---------------------------------------------------------------------------
__global__ void prep_kernel(const float* __restrict__ Cj,
                            const float* __restrict__ W,
                            short* __restrict__ CnPack,
                            short* __restrict__ Wb) {
    const int tid = threadIdx.x;
    if (blockIdx.x < 64) {
        int t = blockIdx.x * 256 + tid;   // 16384 total
        int n = t >> 7, k = t & 127;
        short v = f2bf(W[n * Dn + k]);
        int frag = (n >> 4) * 4 + (k >> 5);
        int lane = ((k >> 3) & 3) * 16 + (n & 15);
        Wb[(frag * 64 + lane) * 8 + (k & 7)] = v;
    } else {
        int c = blockIdx.x - 64;          // 16 blocks
        __shared__ float part[2];
        float v = 0.f, sq = 0.f;
        if (tid < 128) {
            v = Cj[c * Dn + tid];
            sq = v * v;
            #pragma unroll
            for (int off = 32; off > 0; off >>= 1) sq += __shfl_down(sq, off);
        }
        if (tid < 128 && (tid & 63) == 0) part[tid >> 6] = sq;
        __syncthreads();
        if (tid < 128) {
            float cn = v / fmaxf(sqrtf(part[0] + part[1]), EPSV);
            int kt = tid >> 5, ln = ((tid >> 3) & 3) * 16 + c, j = tid & 7;
            CnPack[(kt * 64 + ln) * 8 + j] = f2bf(cn);
        }
    }
}

// ---------------------------------------------------------------------------
// Site kernel: 128-thread blocks = 2 independent waves, one site each, NO
// barriers. Rationale: 64-thr blocks are capped at ~16 WG/CU = 16 waves/CU;
// 2 waves/WG doubles the wave ceiling while __launch_bounds__(128,4) keeps
// the SAME 128-VGPR cap that yields the good ~84-VGPR code (r7/r13).
// VGPR pool then binds at 6 waves/SIMD = 24 waves/CU (+50% residency).
// Agg fused into the Linear nt-loop via per-wave ping-pong LDS tile
// ([2][16][40] = 2.5 KB/wave, intra-wave DS ordering, nt&1 compile-time).
// ---------------------------------------------------------------------------
__launch_bounds__(128, 4)
__global__ void site_kernel(const float* __restrict__ Hs,
                            const short* __restrict__ CnPack,
                            const short* __restrict__ Wb,
                            const float* __restrict__ bvec,
                            const float* __restrict__ imp_in,
                            float* __restrict__ f_out,
                            float* __restrict__ imp_out) {
    // per-wave ping-pong F-tile: [wave][buf][n_local][feature], 80B rows
    __shared__ __align__(16) short Ft[2][2][16][40];   // 5120 B total

    const int lane = threadIdx.x & 63;
    const int wv   = threadIdx.x >> 6;
    const int c16  = lane & 15;
    const int g    = lane >> 4;
    const int site = blockIdx.x * 2 + wv;

    const float* hsrc = Hs + (size_t)site * (Fn * Dn);
    const f32x4 zro = {0.f, 0.f, 0.f, 0.f};

    // ---- issue all global loads early (16 x dwordx4 Hs) ----
    f32x4 x[16];
    #pragma unroll
    for (int kt = 0; kt < 4; ++kt) {
        const f32x4* p0 = (const f32x4*)(hsrc + c16 * Dn + kt * 32 + g * 8);
        const f32x4* p1 = (const f32x4*)(hsrc + (16 + c16) * Dn + kt * 32 + g * 8);
        x[4 * kt + 0] = p0[0];
        x[4 * kt + 1] = p0[1];
        x[4 * kt + 2] = p1[0];
        x[4 * kt + 3] = p1[1];
    }
    bf16x8 bcf[4];
    #pragma unroll
    for (int kt = 0; kt < 4; ++kt)
        bcf[kt] = *(const bf16x8*)&CnPack[(kt * 64 + lane) * 8];
    const float* impp = imp_in + (size_t)site * Fn;
    f32x4 impv0 = *(const f32x4*)(impp + 4 * g);        // imp[4g+r]
    f32x4 impv1 = *(const f32x4*)(impp + 16 + 4 * g);   // imp[16+4g+r]

    // ---- convert to bf16 A-fragments ----
    bf16x8 aF[2][4];
    #pragma unroll
    for (int kt = 0; kt < 4; ++kt) {
        aF[0][kt] = cvt8(x[4 * kt + 0], x[4 * kt + 1]);
        aF[1][kt] = cvt8(x[4 * kt + 2], x[4 * kt + 3]);
    }

    // ---- Gram (row norms via H.H^T diag) + cosine MFMAs (16 MFMA) ----
    f32x4 gm0 = zro, gm1 = zro, cos0 = zro, cos1 = zro;
    #pragma unroll
    for (int kt = 0; kt < 4; ++kt) {
        gm0  = __builtin_amdgcn_mfma_f32_16x16x32_bf16(aF[0][kt], aF[0][kt], gm0, 0, 0, 0);
        gm1  = __builtin_amdgcn_mfma_f32_16x16x32_bf16(aF[1][kt], aF[1][kt], gm1, 0, 0, 0);
        cos0 = __builtin_amdgcn_mfma_f32_16x16x32_bf16(aF[0][kt], bcf[kt], cos0, 0, 0, 0);
        cos1 = __builtin_amdgcn_mfma_f32_16x16x32_bf16(aF[1][kt], bcf[kt], cos1, 0, 0, 0);
    }

    // ---- logits s = 5*cos (softmax-shift-invariant), then e = exp(s).
    //      s in [-5,5] -> exp range-safe; e shared by BOTH softmaxes. ----
    float e0[4], e1[4];
    #pragma unroll
    for (int r = 0; r < 4; ++r) {
        float q0 = __shfl(gm0[r], 20 * g + r);      // diag gather (independent)
        float q1 = __shfl(gm1[r], 20 * g + r);
        float i0 = fastrcp(fmaxf(sqrtf(q0), EPSV));
        float i1 = fastrcp(fmaxf(sqrtf(q1), EPSV));
        e0[r] = __expf(5.0f * cos0[r] * i0);        // f = 4g+r,    c = c16
        e1[r] = __expf(5.0f * cos1[r] * i1);        // f = 16+4g+r, c = c16
    }

    // ---- w: softmax over features -> B-fragment via shuffles ----
    bf16x8 wB;
    {
        float sum = 0.f;
        #pragma unroll
        for (int r = 0; r < 4; ++r) sum += e0[r] + e1[r];
        sum += __shfl_xor(sum, 16);
        sum += __shfl_xor(sum, 32);
        float inv = fastrcp(sum);
        const int srcA = c16 + 16 * ((2 * g) & 3);
        const int srcB = c16 + 16 * ((2 * g + 1) & 3);
        const bool hi = (g >= 2);
        #pragma unroll
        for (int r = 0; r < 4; ++r) {
            float a0 = __shfl(e0[r] * inv, srcA);
            float a1 = __shfl(e1[r] * inv, srcA);
            wB[r] = f2bf(hi ? a1 : a0);
            float b0 = __shfl(e0[r] * inv, srcB);
            float b1 = __shfl(e1[r] * inv, srcB);
            wB[4 + r] = f2bf(hi ? b1 : b0);
        }
    }

    // ---- w3 softmax over centers (DPP row-sums) fused with importance ----
    {
        float t = 0.f;
        #pragma unroll
        for (int h = 0; h < 2; ++h) {
            #pragma unroll
            for (int r = 0; r < 4; ++r) {
                float e = h ? e1[r] : e0[r];
                float q3 = rowsum16(e);             // sum over c (16-lane row)
                t += e * fastrcp(q3) * (h ? impv1[r] : impv0[r]);
            }
        }
        t += __shfl_xor(t, 16);
        t += __shfl_xor(t, 32);
        // importance softmax over c: t <= 32 -> exp safe without max
        float ei = __expf(t);
        float si = rowsum16(ei);
        if (g == 0) imp_out[(size_t)site * Cc + c16] = ei * fastrcp(si);
    }

    // ---- fused Linear + agg: per nt, Linear MFMAs -> tiny LDS tile ->
    //      transposed read -> agg MFMA -> coalesced float4 store ----
    float* op = f_out + (size_t)site * (Cc * Dn);
    #pragma unroll
    for (int nt = 0; nt < 8; ++nt) {
        bf16x8 bw0 = *(const bf16x8*)&Wb[((nt * 4) + 0) * 512 + lane * 8];
        bf16x8 bw1 = *(const bf16x8*)&Wb[((nt * 4) + 1) * 512 + lane * 8];
        bf16x8 bw2 = *(const bf16x8*)&Wb[((nt * 4) + 2) * 512 + lane * 8];
        bf16x8 bw3 = *(const bf16x8*)&Wb[((nt * 4) + 3) * 512 + lane * 8];
        f32x4 acc0 = zro, acc1 = zro;
        acc0 = __builtin_amdgcn_mfma_f32_16x16x32_bf16(aF[0][0], bw0, acc0, 0, 0, 0);
        acc1 = __builtin_amdgcn_mfma_f32_16x16x32_bf16(aF[1][0], bw0, acc1, 0, 0, 0);
        acc0 = __builtin_amdgcn_mfma_f32_16x16x32_bf16(aF[0][1], bw1, acc0, 0, 0, 0);
        acc1 = __builtin_amdgcn_mfma_f32_16x16x32_bf16(aF[1][1], bw1, acc1, 0, 0, 0);
        acc0 = __builtin_amdgcn_mfma_f32_16x16x32_bf16(aF[0][2], bw2, acc0, 0, 0, 0);
        acc1 = __builtin_amdgcn_mfma_f32_16x16x32_bf16(aF[1][2], bw2, acc1, 0, 0, 0);
        acc0 = __builtin_amdgcn_mfma_f32_16x16x32_bf16(aF[0][3], bw3, acc0, 0, 0, 0);
        acc1 = __builtin_amdgcn_mfma_f32_16x16x32_bf16(aF[1][3], bw3, acc1, 0, 0, 0);
        float bb = bvec[nt * 16 + c16];
        bf16x4 p0, p1;
        #pragma unroll
        for (int r = 0; r < 4; ++r) {
            p0[r] = f2bf(fmaxf(acc0[r] + bb, 0.f));
            p1[r] = f2bf(fmaxf(acc1[r] + bb, 0.f));
        }
        // lane holds F[f=4g+r | 16+4g+r][n = 16nt+c16] -> tile row c16
        *(bf16x4*)&Ft[wv][nt & 1][c16][4 * g]      = p0;   // f = 4g+r
        *(bf16x4*)&Ft[wv][nt & 1][c16][16 + 4 * g] = p1;   // f = 16+4g+r
        // transposed read: A-frag for agg = F^T[n_local=c16][f=8g+j]
        bf16x8 aFt = *(const bf16x8*)&Ft[wv][nt & 1][c16][8 * g];
        f32x4 o = __builtin_amdgcn_mfma_f32_16x16x32_bf16(aFt, wB, zro, 0, 0, 0);
        *(f32x4*)(op + c16 * Dn + nt * 16 + 4 * g) = o;
    }
}

// ---------------------------------------------------------------------------
extern "C" void kernel_launch(void* const* d_in, const int* in_sizes, int n_in,
                              void* d_out, int out_size, void* d_ws, size_t ws_size,
                              hipStream_t stream) {
    const float* Hs  = (const float*)d_in[0];
    const float* Cj  = (const float*)d_in[1];
    const float* W   = (const float*)d_in[2];
    const float* b   = (const float*)d_in[3];
    const float* imp = (const float*)d_in[4];

    float* f_out   = (float*)d_out;                          // [B,S,C,D]
    float* imp_out = f_out + (size_t)NSITE * Cc * Dn;        // [B,S,C]

    short* CnPack = (short*)d_ws;                            // 4 KB bf16 frags
    short* Wb     = CnPack + Cc * Dn;                        // 32 KB bf16 frags

    hipLaunchKernelGGL(prep_kernel, dim3(80), dim3(256), 0, stream, Cj, W, CnPack, Wb);
    hipLaunchKernelGGL(site_kernel, dim3(NSITE / 2), dim3(128), 0, stream,
                       Hs, CnPack, Wb, b, imp, f_out, imp_out);
}

// Round 16
// 46.352 us; speedup vs baseline: 1.0474x; 1.0451x over previous
//
#include <hip/hip_runtime.h>
#include <hip/hip_bf16.h>
#include <math.h>

// Problem dims (fixed by reference)
constexpr int Bn = 8, Sn = 1024, Fn = 32, Dn = 128, Cc = 16;
constexpr int NSITE = Bn * Sn;

#define EPSV 1e-8f

typedef __attribute__((ext_vector_type(8))) short bf16x8;
typedef __attribute__((ext_vector_type(4))) short bf16x4;
typedef __attribute__((ext_vector_type(4))) float f32x4;

__device__ inline short f2bf(float x) {
    __hip_bfloat16 h = __float2bfloat16(x);   // RNE
    short s;
    __builtin_memcpy(&s, &h, sizeof(s));
    return s;
}

__device__ inline bf16x8 cvt8(f32x4 x0, f32x4 x1) {
    bf16x8 r;
    r[0] = f2bf(x0[0]); r[1] = f2bf(x0[1]); r[2] = f2bf(x0[2]); r[3] = f2bf(x0[3]);
    r[4] = f2bf(x1[0]); r[5] = f2bf(x1[1]); r[6] = f2bf(x1[2]); r[7] = f2bf(x1[3]);
    return r;
}

// ---- DPP 16-lane rotation all-reduce (VALU-latency, no LDS pipe) ----
template<int CTRL>
__device__ __forceinline__ float dpp_add(float v) {
    union { float f; int i; } u, r;
    u.f = v;
    r.i = __builtin_amdgcn_update_dpp(0, u.i, CTRL, 0xf, 0xf, true);
    return v + r.f;
}
__device__ __forceinline__ float rowsum16(float v) {
    v = dpp_add<0x121>(v);   // row_ror:1
    v = dpp_add<0x122>(v);   // row_ror:2
    v = dpp_add<0x124>(v);   // row_ror:4
    v = dpp_add<0x128>(v);   // row_ror:8
    return v;
}
__device__ __forceinline__ float fastrcp(float x) { return __builtin_amdgcn_rcpf(x); }

// ---------------------------------------------------------------------------
// Fused prep: blocks 0..63 pack W into bf16 MFMA B-fragment layout;
// blocks 64..79 normalize Cj and pack into the same layout.
// frag = (n>>4)*4 + (k>>5); lane = ((k>>3)&3)*16 + (n&15); j = k&7
// ---------------------------------------------------------------------------
__global__ void prep_kernel(const float* __restrict__ Cj,
                            const float* __restrict__ W,
                            short* __restrict__ CnPack,
                            short* __restrict__ Wb) {
    const int tid = threadIdx.x;
    if (blockIdx.x < 64) {
        int t = blockIdx.x * 256 + tid;   // 16384 total
        int n = t >> 7, k = t & 127;
        short v = f2bf(W[n * Dn + k]);
        int frag = (n >> 4) * 4 + (k >> 5);
        int lane = ((k >> 3) & 3) * 16 + (n & 15);
        Wb[(frag * 64 + lane) * 8 + (k & 7)] = v;
    } else {
        int c = blockIdx.x - 64;          // 16 blocks
        __shared__ float part[2];
        float v = 0.f, sq = 0.f;
        if (tid < 128) {
            v = Cj[c * Dn + tid];
            sq = v * v;
            #pragma unroll
            for (int off = 32; off > 0; off >>= 1) sq += __shfl_down(sq, off);
        }
        if (tid < 128 && (tid & 63) == 0) part[tid >> 6] = sq;
        __syncthreads();
        if (tid < 128) {
            float cn = v / fmaxf(sqrtf(part[0] + part[1]), EPSV);
            int kt = tid >> 5, ln = ((tid >> 3) & 3) * 16 + c, j = tid & 7;
            CnPack[(kt * 64 + ln) * 8 + j] = f2bf(cn);
        }
    }
}

// ---------------------------------------------------------------------------
// Site kernel: ONE WAVE = TWO SITES, 64-thread blocks, grid 4096.
// Rationale (r15 evidence): full residency did NOT help -> waves are
// memory-stalled, dominated by per-site re-reads of the 36KB Wb/CnPack
// tables (295 MB of repeat traffic vs 134 MB compulsory). The fused
// Linear nt-loop loads each W fragment ONCE and applies it to BOTH
// sites (Wb requests halved per site; MFMA pipe at 5% absorbs the extra
// work). Sites run r13's phases sequentially; no cross-site prefetch
// (compiler defeats it, r8). Per-wave ping-pong LDS tiles per site.
// ---------------------------------------------------------------------------
__launch_bounds__(64, 4)
__global__ void site_kernel(const float* __restrict__ Hs,
                            const short* __restrict__ CnPack,
                            const short* __restrict__ Wb,
                            const float* __restrict__ bvec,
                            const float* __restrict__ imp_in,
                            float* __restrict__ f_out,
                            float* __restrict__ imp_out) {
    // F-tiles: [site][pingpong][n_local][feature], 80B rows, 5120 B total
    __shared__ __align__(16) short Ft[2][2][16][40];

    const int lane = threadIdx.x;      // 0..63
    const int c16  = lane & 15;
    const int g    = lane >> 4;
    const int sA   = blockIdx.x * 2;
    const int sB   = sA + 1;

    const f32x4 zro = {0.f, 0.f, 0.f, 0.f};

    bf16x8 aFA[2][4], aFB[2][4];
    bf16x8 wBA, wBB;

    // ======== per-site front-end (load + Gram/cos + softmaxes) ========
    #pragma unroll
    for (int sp = 0; sp < 2; ++sp) {
        const int site = sp ? sB : sA;
        bf16x8 (&aF)[2][4] = sp ? aFB : aFA;

        // ---- load Hs -> bf16 A-fragments (16 x dwordx4 burst) ----
        {
            f32x4 x[16];
            const float* hsrc = Hs + (size_t)site * (Fn * Dn);
            #pragma unroll
            for (int kt = 0; kt < 4; ++kt) {
                const f32x4* p0 = (const f32x4*)(hsrc + c16 * Dn + kt * 32 + g * 8);
                const f32x4* p1 = (const f32x4*)(hsrc + (16 + c16) * Dn + kt * 32 + g * 8);
                x[4 * kt + 0] = p0[0];
                x[4 * kt + 1] = p0[1];
                x[4 * kt + 2] = p1[0];
                x[4 * kt + 3] = p1[1];
            }
            #pragma unroll
            for (int kt = 0; kt < 4; ++kt) {
                aF[0][kt] = cvt8(x[4 * kt + 0], x[4 * kt + 1]);
                aF[1][kt] = cvt8(x[4 * kt + 2], x[4 * kt + 3]);
            }
        }

        // ---- Gram (row norms) + cosine MFMAs (16 MFMA); bcf transient ----
        f32x4 gm0 = zro, gm1 = zro, cos0 = zro, cos1 = zro;
        #pragma unroll
        for (int kt = 0; kt < 4; ++kt) {
            bf16x8 bc = *(const bf16x8*)&CnPack[(kt * 64 + lane) * 8];
            gm0  = __builtin_amdgcn_mfma_f32_16x16x32_bf16(aF[0][kt], aF[0][kt], gm0, 0, 0, 0);
            gm1  = __builtin_amdgcn_mfma_f32_16x16x32_bf16(aF[1][kt], aF[1][kt], gm1, 0, 0, 0);
            cos0 = __builtin_amdgcn_mfma_f32_16x16x32_bf16(aF[0][kt], bc, cos0, 0, 0, 0);
            cos1 = __builtin_amdgcn_mfma_f32_16x16x32_bf16(aF[1][kt], bc, cos1, 0, 0, 0);
        }

        // ---- logits + shared exps (no-max softmax, r13-verified) ----
        float e0[4], e1[4];
        #pragma unroll
        for (int r = 0; r < 4; ++r) {
            float q0 = __shfl(gm0[r], 20 * g + r);
            float q1 = __shfl(gm1[r], 20 * g + r);
            float i0 = fastrcp(fmaxf(sqrtf(q0), EPSV));
            float i1 = fastrcp(fmaxf(sqrtf(q1), EPSV));
            e0[r] = __expf(5.0f * cos0[r] * i0);        // f = 4g+r,    c = c16
            e1[r] = __expf(5.0f * cos1[r] * i1);        // f = 16+4g+r, c = c16
        }

        // ---- w: softmax over features -> B-fragment via shuffles ----
        {
            float sum = 0.f;
            #pragma unroll
            for (int r = 0; r < 4; ++r) sum += e0[r] + e1[r];
            sum += __shfl_xor(sum, 16);
            sum += __shfl_xor(sum, 32);
            float inv = fastrcp(sum);
            const int srcA = c16 + 16 * ((2 * g) & 3);
            const int srcB = c16 + 16 * ((2 * g + 1) & 3);
            const bool hi = (g >= 2);
            bf16x8 wB;
            #pragma unroll
            for (int r = 0; r < 4; ++r) {
                float a0 = __shfl(e0[r] * inv, srcA);
                float a1 = __shfl(e1[r] * inv, srcA);
                wB[r] = f2bf(hi ? a1 : a0);
                float b0 = __shfl(e0[r] * inv, srcB);
                float b1 = __shfl(e1[r] * inv, srcB);
                wB[4 + r] = f2bf(hi ? b1 : b0);
            }
            if (sp) wBB = wB; else wBA = wB;
        }

        // ---- w3 softmax over centers (DPP) fused with importance ----
        {
            const float* impp = imp_in + (size_t)site * Fn;
            f32x4 impv0 = *(const f32x4*)(impp + 4 * g);
            f32x4 impv1 = *(const f32x4*)(impp + 16 + 4 * g);
            float t = 0.f;
            #pragma unroll
            for (int h = 0; h < 2; ++h) {
                #pragma unroll
                for (int r = 0; r < 4; ++r) {
                    float e = h ? e1[r] : e0[r];
                    float q3 = rowsum16(e);             // sum over c
                    t += e * fastrcp(q3) * (h ? impv1[r] : impv0[r]);
                }
            }
            t += __shfl_xor(t, 16);
            t += __shfl_xor(t, 32);
            float ei = __expf(t);
            float si = rowsum16(ei);
            if (g == 0) imp_out[(size_t)site * Cc + c16] = ei * fastrcp(si);
        }
    }

    // ======== fused Linear + agg for BOTH sites: Wb loaded ONCE ========
    float* opA = f_out + (size_t)sA * (Cc * Dn);
    float* opB = f_out + (size_t)sB * (Cc * Dn);
    #pragma unroll
    for (int nt = 0; nt < 8; ++nt) {
        f32x4 aA0 = zro, aA1 = zro, aB0 = zro, aB1 = zro;
        #pragma unroll
        for (int kp = 0; kp < 2; ++kp) {
            bf16x8 bw0 = *(const bf16x8*)&Wb[((nt * 4) + 2 * kp + 0) * 512 + lane * 8];
            bf16x8 bw1 = *(const bf16x8*)&Wb[((nt * 4) + 2 * kp + 1) * 512 + lane * 8];
            aA0 = __builtin_amdgcn_mfma_f32_16x16x32_bf16(aFA[0][2 * kp + 0], bw0, aA0, 0, 0, 0);
            aA1 = __builtin_amdgcn_mfma_f32_16x16x32_bf16(aFA[1][2 * kp + 0], bw0, aA1, 0, 0, 0);
            aB0 = __builtin_amdgcn_mfma_f32_16x16x32_bf16(aFB[0][2 * kp + 0], bw0, aB0, 0, 0, 0);
            aB1 = __builtin_amdgcn_mfma_f32_16x16x32_bf16(aFB[1][2 * kp + 0], bw0, aB1, 0, 0, 0);
            aA0 = __builtin_amdgcn_mfma_f32_16x16x32_bf16(aFA[0][2 * kp + 1], bw1, aA0, 0, 0, 0);
            aA1 = __builtin_amdgcn_mfma_f32_16x16x32_bf16(aFA[1][2 * kp + 1], bw1, aA1, 0, 0, 0);
            aB0 = __builtin_amdgcn_mfma_f32_16x16x32_bf16(aFB[0][2 * kp + 1], bw1, aB0, 0, 0, 0);
            aB1 = __builtin_amdgcn_mfma_f32_16x16x32_bf16(aFB[1][2 * kp + 1], bw1, aB1, 0, 0, 0);
        }
        float bb = bvec[nt * 16 + c16];
        // site A epilogue
        {
            bf16x4 p0, p1;
            #pragma unroll
            for (int r = 0; r < 4; ++r) {
                p0[r] = f2bf(fmaxf(aA0[r] + bb, 0.f));
                p1[r] = f2bf(fmaxf(aA1[r] + bb, 0.f));
            }
            *(bf16x4*)&Ft[0][nt & 1][c16][4 * g]      = p0;
            *(bf16x4*)&Ft[0][nt & 1][c16][16 + 4 * g] = p1;
            bf16x8 aFt = *(const bf16x8*)&Ft[0][nt & 1][c16][8 * g];
            f32x4 o = __builtin_amdgcn_mfma_f32_16x16x32_bf16(aFt, wBA, zro, 0, 0, 0);
            *(f32x4*)(opA + c16 * Dn + nt * 16 + 4 * g) = o;
        }
        // site B epilogue
        {
            bf16x4 p0, p1;
            #pragma unroll
            for (int r = 0; r < 4; ++r) {
                p0[r] = f2bf(fmaxf(aB0[r] + bb, 0.f));
                p1[r] = f2bf(fmaxf(aB1[r] + bb, 0.f));
            }
            *(bf16x4*)&Ft[1][nt & 1][c16][4 * g]      = p0;
            *(bf16x4*)&Ft[1][nt & 1][c16][16 + 4 * g] = p1;
            bf16x8 aFt = *(const bf16x8*)&Ft[1][nt & 1][c16][8 * g];
            f32x4 o = __builtin_amdgcn_mfma_f32_16x16x32_bf16(aFt, wBB, zro, 0, 0, 0);
            *(f32x4*)(opB + c16 * Dn + nt * 16 + 4 * g) = o;
        }
    }
}

// ---------------------------------------------------------------------------
extern "C" void kernel_launch(void* const* d_in, const int* in_sizes, int n_in,
                              void* d_out, int out_size, void* d_ws, size_t ws_size,
                              hipStream_t stream) {
    const float* Hs  = (const float*)d_in[0];
    const float* Cj  = (const float*)d_in[1];
    const float* W   = (const float*)d_in[2];
    const float* b   = (const float*)d_in[3];
    const float* imp = (const float*)d_in[4];

    float* f_out   = (float*)d_out;                          // [B,S,C,D]
    float* imp_out = f_out + (size_t)NSITE * Cc * Dn;        // [B,S,C]

    short* CnPack = (short*)d_ws;                            // 4 KB bf16 frags
    short* Wb     = CnPack + Cc * Dn;                        // 32 KB bf16 frags

    hipLaunchKernelGGL(prep_kernel, dim3(80), dim3(256), 0, stream, Cj, W, CnPack, Wb);
    hipLaunchKernelGGL(site_kernel, dim3(NSITE / 2), dim3(64), 0, stream,
                       Hs, CnPack, Wb, b, imp, f_out, imp_out);
}